// Round 2
// baseline (339.298 us; speedup 1.0000x reference)
//
#include <hip/hip_runtime.h>

#define BB 64
#define TT 2000
#define DENC 512
#define IDIM 512
#define HID 256
#define KK 10

// Fully fused MOL-attention forward. One block per batch element.
//
// Exploits two structural facts:
//  * softmax over the singleton N axis => weights == 1 exactly, so the
//    3k+2 output channels of the MLP are never needed.
//  * align[b,j] = sum_k sig((j+.5-m)/s) - sig((j-.5-m)/s) is exactly 0 in
//    fp32 outside a narrow j-window (means/scales ~ exp(N(0,~0.3)) ~ 1),
//    so context only needs the rows with |align| > 1e-8 (error bound
//    2000*1e-8*max|enc| ~ 1e-4 << 0.319 threshold; falls back gracefully
//    to the full 262 MB read if the window were ever wide).
//
// d_out layout: [ context (BB*DENC) | align (BB*TT) ]  — written fully, no
// zero-init or atomics needed. d_ws unused.
__global__ __launch_bounds__(256) void molattn_fused(
    const float* __restrict__ state,
    const float* __restrict__ enc,
    const float* __restrict__ W1,
    const float* __restrict__ b1,
    const float* __restrict__ W2,
    const float* __restrict__ b2,
    float* __restrict__ out) {
    __shared__ __align__(16) float s_state[IDIM];   // 2 KB
    __shared__ float s_h[HID];                      // 1 KB
    __shared__ float s_ms[2 * KK];                  // 80 B
    __shared__ float s_align[TT];                   // 8 KB
    __shared__ int s_jmax;

    const int b = blockIdx.x;
    const int t = threadIdx.x;

    // ---- Phase 1: h = tanh(W1 @ state + b1) ----
    const float* st = state + (size_t)b * IDIM;
    s_state[t]       = st[t];
    s_state[t + 256] = st[t + 256];
    if (t == 0) s_jmax = -1;
    __syncthreads();

    const float* w1r = W1 + (size_t)t * IDIM;
    float sum = 0.f;
#pragma unroll 8
    for (int k = 0; k < IDIM; k += 4) {
        float4 w = *(const float4*)(w1r + k);
        float4 s = *(const float4*)(s_state + k);
        sum += w.x * s.x + w.y * s.y + w.z * s.z + w.w * s.w;
    }
    s_h[t] = tanhf(sum + b1[t]);
    __syncthreads();

    // ---- Phase 2: means (exp(z_{3k})) and inverse scales (exp(-z_{3k+1})) ----
    if (t < 2 * KK) {
        const int k = t >> 1;
        const int which = t & 1;                 // 0 -> mean, 1 -> inv-scale
        const int o = 3 * k + which;
        const float* w2r = W2 + o * HID;
        float z = 0.f;
#pragma unroll 4
        for (int i = 0; i < HID; i++) z += w2r[i] * s_h[i];
        z += b2[o];
        s_ms[t] = (which == 0) ? expf(z) : expf(-z);
    }
    __syncthreads();

    // ---- Phase 3: align[b,j] for all j; track max active j ----
    float* out_align = out + BB * DENC + (size_t)b * TT;
    int my_jmax = -1;
    for (int j = t; j < TT; j += 256) {
        const float fj = (float)j;
        float a = 0.f;
#pragma unroll
        for (int k = 0; k < KK; k++) {
            const float mean = s_ms[2 * k];
            const float is   = s_ms[2 * k + 1];
            const float x1 = (fj + 0.5f - mean) * is;
            const float x2 = (fj - 0.5f - mean) * is;
            a += 1.f / (1.f + expf(-x1)) - 1.f / (1.f + expf(-x2));
        }
        s_align[j] = a;
        out_align[j] = a;
        if (fabsf(a) > 1e-8f) my_jmax = j;       // j ascending per thread
    }
    if (my_jmax >= 0) atomicMax(&s_jmax, my_jmax);
    __syncthreads();
    const int jmax = s_jmax;

    // ---- Phase 4: context[b,d] = sum_j align * enc[b,j,d], d = 2t, 2t+1 ----
    const int d = t * 2;
    const float* ebase = enc + (size_t)b * TT * DENC + d;
    float2 acc = make_float2(0.f, 0.f);
    for (int j = 0; j <= jmax; j++) {
        const float a = s_align[j];              // LDS broadcast, uniform branch
        if (fabsf(a) > 1e-8f) {
            const float2 v = *(const float2*)(ebase + (size_t)j * DENC);
            acc.x += a * v.x;
            acc.y += a * v.y;
        }
    }
    float* ctx = out + (size_t)b * DENC;
    ctx[d]     = acc.x;
    ctx[d + 1] = acc.y;
}

extern "C" void kernel_launch(void* const* d_in, const int* in_sizes, int n_in,
                              void* d_out, int out_size, void* d_ws, size_t ws_size,
                              hipStream_t stream) {
    const float* state = (const float*)d_in[0];
    const float* enc_z = (const float*)d_in[1];
    const float* W1    = (const float*)d_in[2];
    const float* b1    = (const float*)d_in[3];
    const float* W2    = (const float*)d_in[4];
    const float* b2    = (const float*)d_in[5];
    float* out = (float*)d_out;

    molattn_fused<<<BB, 256, 0, stream>>>(state, enc_z, W1, b1, W2, b2, out);
}